// Round 14
// baseline (148.956 us; speedup 1.0000x reference)
//
#include <hip/hip_runtime.h>
#include <math.h>

#define NN 32768      // nodes
#define NE 524288     // edges
#define NH 16384      // hosts
#define NG 64         // graphs
#define OUTC 2050     // 2 + 256*8
#define CAP 64        // padded-CSR slots per node (max degree ~40 for Binomial(E,1/N))

typedef _Float16 f16x8 __attribute__((ext_vector_type(8)));
typedef float f32x4 __attribute__((ext_vector_type(4)));

__device__ inline unsigned short f16bits(_Float16 h) { return __builtin_bit_cast(unsigned short, h); }

// async global->LDS, 16B per lane; LDS dest = wave-uniform base + lane*16 (linear)
__device__ inline void gll16(const ushort* g, ushort* l) {
    __builtin_amdgcn_global_load_lds(
        (const __attribute__((address_space(1))) unsigned int*)g,
        (__attribute__((address_space(3))) unsigned int*)l, 16, 0, 0);
}

// int64 edges stored little-endian have zero odd words (values < 2^31).
__device__ inline int detect64(const int* __restrict__ ei) {
    int o = 0;
#pragma unroll
    for (int i = 1; i < 32; i += 2) o |= ei[i];
    return o == 0;
}

// ---------------- weight prep (+ deg zeroing); runs FIRST ----------------
__global__ __launch_bounds__(256) void k_wprep(const float* __restrict__ W1, const float* __restrict__ W2,
                                               const float* __restrict__ Wo1, const float* __restrict__ Wo2,
                                               ushort* __restrict__ w1h, ushort* __restrict__ w1l,
                                               ushort* __restrict__ w2h, ushort* __restrict__ w2l,
                                               ushort* __restrict__ o1h, ushort* __restrict__ o1l,
                                               ushort* __restrict__ o2h, ushort* __restrict__ o2l,
                                               int* __restrict__ deg) {
    int b = blockIdx.x, t = threadIdx.x;
    int gid = b * 256 + t;
    if (gid < NN) deg[gid] = 0;
    const float* src; ushort *dh, *dl; int K, N, base;
    if (b < 128)      { src = W1;  dh = w1h; dl = w1l; K = 128; N = 256; base = b * 256; }
    else if (b < 192) { src = W2;  dh = w2h; dl = w2l; K = 256; N = 64;  base = (b - 128) * 256; }
    else if (b < 256) { src = Wo1; dh = o1h; dl = o1l; K = 64;  N = 256; base = (b - 192) * 256; }
    else              { src = Wo2; dh = o2h; dl = o2l; K = 256; N = 256; base = (b - 256) * 256; }
    int idx = base + t;          // index over [N][K], coalesced writes
    int n = idx / K, k = idx % K;
    float v = src[(size_t)k * N + n];
    _Float16 h = (_Float16)v;
    _Float16 l = (_Float16)(v - (float)h);
    dh[idx] = f16bits(h);
    dl[idx] = f16bits(l);
}

// ---------------- one-pass padded-CSR build: deg count + neighbor fill ----------------
__global__ __launch_bounds__(256) void k_build(const int* __restrict__ ei,
                                               int* __restrict__ deg, int* __restrict__ csr2) {
    int e = blockIdx.x * 256 + threadIdx.x;
    if (e >= NE) return;
    int is64 = detect64(ei);
    int s = is64 ? ei[2 * e] : ei[e];
    int d = is64 ? ei[2 * NE + 2 * e] : ei[NE + e];
    int p = atomicAdd(&deg[d], 1);
    if (p < CAP) csr2[(d << 6) + p] = s;
}

// ---------------- dinv table: dinvt[i] = rsqrt(deg[i]+1) ----------------
__global__ __launch_bounds__(256) void k_dinv(const int* __restrict__ deg, float* __restrict__ dinvt) {
    int i = blockIdx.x * 256 + threadIdx.x;
    dinvt[i] = rsqrtf((float)(deg[i] + 1));
}

// ================= fused GCN stage A: gather-agg(x) -> @W1+b1,relu -> @W2 =================
// BM=16. LDS 48 KB -> 3 blocks/CU (24 waves/CU: +50% gather parallelism vs BM=32).
// Phase0: conv1 aggregation, 32 thr/node x 4 dims. Stage1: T1[16,256]=relu(AF@W1T+b1).
// Stage2: h2pre[16,64]=T1@W2T (waves 0-3 compute; all stage).
__global__ __launch_bounds__(512, 6) void k_fg1(const float* __restrict__ x, const int* __restrict__ deg,
                                                const int* __restrict__ csr2, const float* __restrict__ dinvt,
                                                const ushort* __restrict__ B1h, const ushort* __restrict__ B1l,
                                                const float* __restrict__ b1v,
                                                const ushort* __restrict__ B2h, const ushort* __restrict__ B2l,
                                                float* __restrict__ C) {
    __shared__ ushort T1[2][16][256];    // 16 KB; stage1 uses cols [0,128) as AF
    __shared__ ushort Bs[2][256][32];    // 32 KB, linear (stage 1 & 2)

    int t = threadIdx.x;
    int bm = blockIdx.x * 16;
    int wave = t >> 6, lane = t & 63;
    int l15 = lane & 15, lk = lane >> 4;
    int lr = lane >> 2, lp = lane & 3;

    // ---------- phase 0: conv1 gather-aggregate (32 thr/node, 4 dims, 8-wide) ----------
    {
        int nl = t >> 5;                 // node-local 0..15
        int dgb = (t & 31) * 4;          // dim-group base
        int node = bm + nl;
        int n = min(deg[node], CAP);
        float dd = dinvt[node];
        float4 s0 = *(const float4*)(x + (size_t)node * 128 + dgb);
        float ac[4] = {s0.x * dd, s0.y * dd, s0.z * dd, s0.w * dd};
        const int* cl = csr2 + (node << 6);
        int i = 0;
        for (; i + 8 <= n; i += 8) {
            int4 c0 = *(const int4*)(cl + i);
            int4 c1 = *(const int4*)(cl + i + 4);
            int ss[8] = {c0.x, c0.y, c0.z, c0.w, c1.x, c1.y, c1.z, c1.w};
            float wv[8]; float4 vv[8];
#pragma unroll
            for (int j = 0; j < 8; ++j) wv[j] = dinvt[ss[j]];
#pragma unroll
            for (int j = 0; j < 8; ++j) vv[j] = *(const float4*)(x + (size_t)ss[j] * 128 + dgb);
#pragma unroll
            for (int j = 0; j < 8; ++j) {
                ac[0] += vv[j].x * wv[j]; ac[1] += vv[j].y * wv[j];
                ac[2] += vv[j].z * wv[j]; ac[3] += vv[j].w * wv[j];
            }
        }
        for (; i + 4 <= n; i += 4) {
            int4 c0 = *(const int4*)(cl + i);
            int ss[4] = {c0.x, c0.y, c0.z, c0.w};
            float wv[4]; float4 vv[4];
#pragma unroll
            for (int j = 0; j < 4; ++j) wv[j] = dinvt[ss[j]];
#pragma unroll
            for (int j = 0; j < 4; ++j) vv[j] = *(const float4*)(x + (size_t)ss[j] * 128 + dgb);
#pragma unroll
            for (int j = 0; j < 4; ++j) {
                ac[0] += vv[j].x * wv[j]; ac[1] += vv[j].y * wv[j];
                ac[2] += vv[j].z * wv[j]; ac[3] += vv[j].w * wv[j];
            }
        }
        for (; i < n; ++i) {
            int s = cl[i];
            float wv = dinvt[s];
            float4 v0 = *(const float4*)(x + (size_t)s * 128 + dgb);
            ac[0] += v0.x * wv; ac[1] += v0.y * wv; ac[2] += v0.z * wv; ac[3] += v0.w * wv;
        }
        ushort hv[4], lv[4];
#pragma unroll
        for (int j = 0; j < 4; ++j) {
            float v = ac[j] * dd;
            _Float16 h = (_Float16)v;
            _Float16 l = (_Float16)(v - (float)h);
            hv[j] = f16bits(h); lv[j] = f16bits(l);
        }
        int c = dgb >> 3, half = (dgb >> 2) & 1;
        int pos = ((c ^ (nl & 7)) << 3) + half * 4;   // swizzled
        *(uint2*)&T1[0][nl][pos] = *(const uint2*)hv;
        *(uint2*)&T1[1][nl][pos] = *(const uint2*)lv;
    }
    __syncthreads();

    // ---------- stage 1: K1=128, N=256; wave wc: rows 0..15 x cols wc*32..+32 ----------
    int wc = wave;
    f32x4 acc1[2];
#pragma unroll
    for (int ni = 0; ni < 2; ++ni) acc1[ni] = (f32x4){0.f, 0.f, 0.f, 0.f};

    for (int k0 = 0; k0 < 128; k0 += 32) {
#pragma unroll
        for (int i = 0; i < 4; ++i) {   // B1: 32 x 1KB units
            int u = wave * 4 + i;
            int buf = u >> 4, rb = (u & 15) * 16;
            int r = rb + lr;
            int cq = lp ^ ((r >> 1) & 3);
            gll16((buf ? B1l : B1h) + (size_t)r * 128 + k0 + cq * 8, &Bs[buf][rb][0]);
        }
        __syncthreads();
        f16x8 ah, al, bh[2], bl[2];
        {
            int r = l15;
            int pos = (((k0 >> 3) + lk) ^ (r & 7)) * 8;
            ah = *(const f16x8*)&T1[0][r][pos];
            al = *(const f16x8*)&T1[1][r][pos];
        }
#pragma unroll
        for (int ni = 0; ni < 2; ++ni) {
            int r = wc * 32 + ni * 16 + l15;
            int pos = (lk ^ ((r >> 1) & 3)) * 8;
            bh[ni] = *(const f16x8*)&Bs[0][r][pos];
            bl[ni] = *(const f16x8*)&Bs[1][r][pos];
        }
#pragma unroll
        for (int ni = 0; ni < 2; ++ni) {
            acc1[ni] = __builtin_amdgcn_mfma_f32_16x16x32_f16(ah, bh[ni], acc1[ni], 0, 0, 0);
            acc1[ni] = __builtin_amdgcn_mfma_f32_16x16x32_f16(ah, bl[ni], acc1[ni], 0, 0, 0);
            acc1[ni] = __builtin_amdgcn_mfma_f32_16x16x32_f16(al, bh[ni], acc1[ni], 0, 0, 0);
        }
        __syncthreads();
    }

    // T1 epilogue: bias + relu + split, swizzled store
    float bb0 = b1v[wc * 32 + l15];
    float bb1 = b1v[wc * 32 + 16 + l15];
#pragma unroll
    for (int ni = 0; ni < 2; ++ni)
#pragma unroll
        for (int r = 0; r < 4; ++r) {
            int row = lk * 4 + r;                     // 0..15
            int col = wc * 32 + ni * 16 + l15;
            float v = fmaxf(acc1[ni][r] + (ni ? bb1 : bb0), 0.f);
            _Float16 h = (_Float16)v;
            _Float16 l = (_Float16)(v - (float)h);
            int off = (((col >> 3) ^ (row & 7)) << 3) | (col & 7);
            T1[0][row][off] = f16bits(h);
            T1[1][row][off] = f16bits(l);
        }
    __syncthreads();

    // ---------- stage 2: K2=256, N2=64; 16x64 out -> waves 0-3 compute ----------
    f32x4 acc2 = (f32x4){0.f, 0.f, 0.f, 0.f};
    for (int k0 = 0; k0 < 256; k0 += 32) {
        {   // 8 x 1KB units (rows 0..63)
            int buf = wave >> 2, rb = (wave & 3) * 16;
            int r = rb + lr;
            int cq = lp ^ ((r >> 1) & 3);
            gll16((buf ? B2l : B2h) + (size_t)r * 256 + k0 + cq * 8, &Bs[buf][rb][0]);
        }
        __syncthreads();
        if (wave < 4) {
            int row = l15;
            int off = (((k0 >> 3) + lk) ^ (row & 7)) << 3;
            f16x8 ah = *(const f16x8*)&T1[0][row][off];
            f16x8 al = *(const f16x8*)&T1[1][row][off];
            int r = wave * 16 + l15;
            int pos = (lk ^ ((r >> 1) & 3)) * 8;
            f16x8 bh = *(const f16x8*)&Bs[0][r][pos];
            f16x8 bl = *(const f16x8*)&Bs[1][r][pos];
            acc2 = __builtin_amdgcn_mfma_f32_16x16x32_f16(ah, bh, acc2, 0, 0, 0);
            acc2 = __builtin_amdgcn_mfma_f32_16x16x32_f16(ah, bl, acc2, 0, 0, 0);
            acc2 = __builtin_amdgcn_mfma_f32_16x16x32_f16(al, bh, acc2, 0, 0, 0);
        }
        __syncthreads();
    }
    if (wave < 4) {
#pragma unroll
        for (int r = 0; r < 4; ++r) {
            int row = bm + lk * 4 + r;
            int col = wave * 16 + l15;
            C[(size_t)row * 64 + col] = acc2[r];
        }
    }
}

// ================= fused MLP stage B: conv2-agg(h2pre) -> @Wo1+bo1,relu -> @Wo2+bo2,relu =================
// BM=16, 48 KB LDS -> 3 blocks/CU. Phase0: 32 thr/row x 2 dims.
__global__ __launch_bounds__(512, 6) void k_fg2(const float* __restrict__ h2, const int* __restrict__ deg,
                                                const int* __restrict__ csr2, const float* __restrict__ dinvt,
                                                const float* __restrict__ b2v,
                                                const ushort* __restrict__ B1h, const ushort* __restrict__ B1l,
                                                const float* __restrict__ b1v,
                                                const ushort* __restrict__ B2h, const ushort* __restrict__ B2l,
                                                const float* __restrict__ bo2v,
                                                float* __restrict__ C) {
    __shared__ ushort T1[2][16][256];    // stage1 uses cols [0,64) as AF
    __shared__ ushort Bs[2][256][32];

    int t = threadIdx.x;
    int bm = blockIdx.x * 16;
    int wave = t >> 6, lane = t & 63;
    int l15 = lane & 15, lk = lane >> 4;
    int lr = lane >> 2, lp = lane & 3;

    // ---------- phase 0: conv2 gather-aggregate (host rows; 32 thr/row, 2 dims, 8-wide) ----------
    {
        int nl = t >> 5;                          // row-local 0..15
        int hr = bm + nl;                         // host row
        int node = ((hr >> 8) << 9) | (hr & 255);
        int dgb = (t & 31) * 2;
        int n = min(deg[node], CAP);
        float dd = dinvt[node];
        float2 s = *(const float2*)(h2 + (size_t)node * 64 + dgb);
        float ac[2] = {s.x * dd, s.y * dd};
        const int* cl = csr2 + (node << 6);
        int i = 0;
        for (; i + 8 <= n; i += 8) {
            int4 c0 = *(const int4*)(cl + i);
            int4 c1 = *(const int4*)(cl + i + 4);
            int ss[8] = {c0.x, c0.y, c0.z, c0.w, c1.x, c1.y, c1.z, c1.w};
            float wv[8]; float2 vv[8];
#pragma unroll
            for (int j = 0; j < 8; ++j) wv[j] = dinvt[ss[j]];
#pragma unroll
            for (int j = 0; j < 8; ++j) vv[j] = *(const float2*)(h2 + (size_t)ss[j] * 64 + dgb);
#pragma unroll
            for (int j = 0; j < 8; ++j) { ac[0] += vv[j].x * wv[j]; ac[1] += vv[j].y * wv[j]; }
        }
        for (; i + 4 <= n; i += 4) {
            int4 c0 = *(const int4*)(cl + i);
            int ss[4] = {c0.x, c0.y, c0.z, c0.w};
            float wv[4]; float2 vv[4];
#pragma unroll
            for (int j = 0; j < 4; ++j) wv[j] = dinvt[ss[j]];
#pragma unroll
            for (int j = 0; j < 4; ++j) vv[j] = *(const float2*)(h2 + (size_t)ss[j] * 64 + dgb);
#pragma unroll
            for (int j = 0; j < 4; ++j) { ac[0] += vv[j].x * wv[j]; ac[1] += vv[j].y * wv[j]; }
        }
        for (; i < n; ++i) {
            int sI = cl[i];
            float wv = dinvt[sI];
            float2 vv = *(const float2*)(h2 + (size_t)sI * 64 + dgb);
            ac[0] += vv.x * wv; ac[1] += vv.y * wv;
        }
        ushort hv[2], lv[2];
#pragma unroll
        for (int j = 0; j < 2; ++j) {
            float v = fmaxf(ac[j] * dd + b2v[dgb + j], 0.f);
            _Float16 h = (_Float16)v;
            _Float16 l = (_Float16)(v - (float)h);
            hv[j] = f16bits(h); lv[j] = f16bits(l);
        }
        int c = dgb >> 3, sub = dgb & 7;
        int pos = ((c ^ (nl & 7)) << 3) + sub;
        *(uint*)&T1[0][nl][pos] = *(const uint*)hv;
        *(uint*)&T1[1][nl][pos] = *(const uint*)lv;
    }
    __syncthreads();

    // ---------- stage 1: K1=64, N=256 ----------
    int wc = wave;
    f32x4 acc1[2];
#pragma unroll
    for (int ni = 0; ni < 2; ++ni) acc1[ni] = (f32x4){0.f, 0.f, 0.f, 0.f};

    for (int k0 = 0; k0 < 64; k0 += 32) {
#pragma unroll
        for (int i = 0; i < 4; ++i) {   // B1: 32 x 1KB units
            int u = wave * 4 + i;
            int buf = u >> 4, rb = (u & 15) * 16;
            int r = rb + lr;
            int cq = lp ^ ((r >> 1) & 3);
            gll16((buf ? B1l : B1h) + (size_t)r * 64 + k0 + cq * 8, &Bs[buf][rb][0]);
        }
        __syncthreads();
        f16x8 ah, al, bh[2], bl[2];
        {
            int r = l15;
            int pos = (((k0 >> 3) + lk) ^ (r & 7)) * 8;
            ah = *(const f16x8*)&T1[0][r][pos];
            al = *(const f16x8*)&T1[1][r][pos];
        }
#pragma unroll
        for (int ni = 0; ni < 2; ++ni) {
            int r = wc * 32 + ni * 16 + l15;
            int pos = (lk ^ ((r >> 1) & 3)) * 8;
            bh[ni] = *(const f16x8*)&Bs[0][r][pos];
            bl[ni] = *(const f16x8*)&Bs[1][r][pos];
        }
#pragma unroll
        for (int ni = 0; ni < 2; ++ni) {
            acc1[ni] = __builtin_amdgcn_mfma_f32_16x16x32_f16(ah, bh[ni], acc1[ni], 0, 0, 0);
            acc1[ni] = __builtin_amdgcn_mfma_f32_16x16x32_f16(ah, bl[ni], acc1[ni], 0, 0, 0);
            acc1[ni] = __builtin_amdgcn_mfma_f32_16x16x32_f16(al, bh[ni], acc1[ni], 0, 0, 0);
        }
        __syncthreads();
    }

    // T1 epilogue
    float bb0 = b1v[wc * 32 + l15];
    float bb1 = b1v[wc * 32 + 16 + l15];
#pragma unroll
    for (int ni = 0; ni < 2; ++ni)
#pragma unroll
        for (int r = 0; r < 4; ++r) {
            int row = lk * 4 + r;                    // 0..15
            int col = wc * 32 + ni * 16 + l15;
            float v = fmaxf(acc1[ni][r] + (ni ? bb1 : bb0), 0.f);
            _Float16 h = (_Float16)v;
            _Float16 l = (_Float16)(v - (float)h);
            int off = (((col >> 3) ^ (row & 7)) << 3) | (col & 7);
            T1[0][row][off] = f16bits(h);
            T1[1][row][off] = f16bits(l);
        }
    __syncthreads();

    // ---------- stage 2: K2=256, N2=256; 16x256 out -> 8 waves x 2 n-frags ----------
    f32x4 acc2[2];
#pragma unroll
    for (int ni = 0; ni < 2; ++ni) acc2[ni] = (f32x4){0.f, 0.f, 0.f, 0.f};

    for (int k0 = 0; k0 < 256; k0 += 32) {
#pragma unroll
        for (int i = 0; i < 4; ++i) {   // 32 x 1KB units
            int u = wave * 4 + i;
            int buf = u >> 4, rb = (u & 15) * 16;
            int r = rb + lr;
            int cq = lp ^ ((r >> 1) & 3);
            gll16((buf ? B2l : B2h) + (size_t)r * 256 + k0 + cq * 8, &Bs[buf][rb][0]);
        }
        __syncthreads();
        f16x8 ah, al, bh[2], bl[2];
        {
            int row = l15;
            int off = (((k0 >> 3) + lk) ^ (row & 7)) << 3;
            ah = *(const f16x8*)&T1[0][row][off];
            al = *(const f16x8*)&T1[1][row][off];
        }
#pragma unroll
        for (int ni = 0; ni < 2; ++ni) {
            int r = wave * 32 + ni * 16 + l15;
            int pos = (lk ^ ((r >> 1) & 3)) * 8;
            bh[ni] = *(const f16x8*)&Bs[0][r][pos];
            bl[ni] = *(const f16x8*)&Bs[1][r][pos];
        }
#pragma unroll
        for (int ni = 0; ni < 2; ++ni) {
            acc2[ni] = __builtin_amdgcn_mfma_f32_16x16x32_f16(ah, bh[ni], acc2[ni], 0, 0, 0);
            acc2[ni] = __builtin_amdgcn_mfma_f32_16x16x32_f16(ah, bl[ni], acc2[ni], 0, 0, 0);
            acc2[ni] = __builtin_amdgcn_mfma_f32_16x16x32_f16(al, bh[ni], acc2[ni], 0, 0, 0);
        }
        __syncthreads();
    }
    // epilogue: fp32 global write
    float cb0 = bo2v[wave * 32 + l15];
    float cb1 = bo2v[wave * 32 + 16 + l15];
#pragma unroll
    for (int ni = 0; ni < 2; ++ni)
#pragma unroll
        for (int r = 0; r < 4; ++r) {
            int row = bm + lk * 4 + r;
            int col = wave * 32 + ni * 16 + l15;
            float v = fmaxf(acc2[ni][r] + (ni ? cb1 : cb0), 0.f);
            C[(size_t)row * 256 + col] = v;
        }
}

// ---------------- fused head: logits = a2 @ Wo3 + bo3, then per-graph softmax ----------------
__global__ __launch_bounds__(256) void k_head(const float* __restrict__ A, const float* __restrict__ W,
                                              const float* __restrict__ bias, float* __restrict__ out) {
    __shared__ float Ws[2048];
    __shared__ float rm[4], rs[4];
    int g = blockIdx.x, t = threadIdx.x;
#pragma unroll
    for (int i = 0; i < 8; ++i) Ws[t + 256 * i] = W[t + 256 * i];   // [k][a] row-major
    __syncthreads();
    const float* arow = A + ((size_t)g * 256 + t) * 256;
    float acc[8];
#pragma unroll
    for (int a = 0; a < 8; ++a) acc[a] = bias[a];
    for (int k = 0; k < 256; k += 8) {
        float4 v0 = *(const float4*)(arow + k);
        float4 v1 = *(const float4*)(arow + k + 4);
#pragma unroll
        for (int a = 0; a < 8; ++a) {
            acc[a] += v0.x * Ws[(k + 0) * 8 + a] + v0.y * Ws[(k + 1) * 8 + a]
                    + v0.z * Ws[(k + 2) * 8 + a] + v0.w * Ws[(k + 3) * 8 + a]
                    + v1.x * Ws[(k + 4) * 8 + a] + v1.y * Ws[(k + 5) * 8 + a]
                    + v1.z * Ws[(k + 6) * 8 + a] + v1.w * Ws[(k + 7) * 8 + a];
        }
    }
    float m = acc[0];
#pragma unroll
    for (int i = 1; i < 8; ++i) m = fmaxf(m, acc[i]);
    for (int off = 32; off; off >>= 1) m = fmaxf(m, __shfl_xor(m, off));
    if ((t & 63) == 0) rm[t >> 6] = m;
    __syncthreads();
    m = fmaxf(fmaxf(rm[0], rm[1]), fmaxf(rm[2], rm[3]));
    float e[8];
    float s = 0.f;
#pragma unroll
    for (int i = 0; i < 8; ++i) { e[i] = expf(acc[i] - m); s += e[i]; }
    for (int off = 32; off; off >>= 1) s += __shfl_xor(s, off);
    if ((t & 63) == 0) rs[t >> 6] = s;
    __syncthreads();
    s = rs[0] + rs[1] + rs[2] + rs[3];
    float inv = 1.f / s;
    float* ob = out + (size_t)g * OUTC;
    if (t < 2) ob[t] = 0.f;
#pragma unroll
    for (int a = 0; a < 8; ++a) ob[2 + a * 256 + t] = e[a] * inv;
}

extern "C" void kernel_launch(void* const* d_in, const int* in_sizes, int n_in,
                              void* d_out, int out_size, void* d_ws, size_t ws_size,
                              hipStream_t stream) {
    const float* x   = (const float*)d_in[0];
    const int*   ei  = (const int*)d_in[1];
    const float* W1  = (const float*)d_in[3];
    const float* b1  = (const float*)d_in[4];
    const float* W2  = (const float*)d_in[5];
    const float* b2  = (const float*)d_in[6];
    const float* Wo1 = (const float*)d_in[7];
    const float* bo1 = (const float*)d_in[8];
    const float* Wo2 = (const float*)d_in[9];
    const float* bo2 = (const float*)d_in[10];
    const float* Wo3 = (const float*)d_in[11];
    const float* bo3 = (const float*)d_in[12];
    float* out = (float*)d_out;

    char* w = (char*)d_ws;
    float*  h2pre  = (float*) (w + (0ull  << 20));   // 8MB  [32768][64]
    float*  a2     = (float*) (w + (8ull  << 20));   // 16MB [16384][256]
    char* p = w + (24ull << 20);                     // transposed split weights
    ushort* w1h = (ushort*)p; p += 65536;
    ushort* w1l = (ushort*)p; p += 65536;
    ushort* w2h = (ushort*)p; p += 32768;
    ushort* w2l = (ushort*)p; p += 32768;
    ushort* o1h = (ushort*)p; p += 32768;
    ushort* o1l = (ushort*)p; p += 32768;
    ushort* o2h = (ushort*)p; p += 131072;
    ushort* o2l = (ushort*)p; p += 131072;
    char* misc = w + (25ull << 20);
    int*   deg   = (int*)misc;                       // 128KB
    int*   csr2  = deg + NN;                         // 8MB padded CSR [NN][CAP]
    float* dinvt = (float*)(csr2 + (size_t)NN * CAP);// 128KB

    // wprep: transposes weights AND zeroes deg
    k_wprep<<<512, 256, 0, stream>>>(W1, W2, Wo1, Wo2, w1h, w1l, w2h, w2l, o1h, o1l, o2h, o2l, deg);
    // one-pass padded-CSR build
    k_build<<<NE / 256, 256, 0, stream>>>(ei, deg, csr2);
    // dinv table
    k_dinv<<<NN / 256, 256, 0, stream>>>(deg, dinvt);

    // fused: conv1-agg + @W1+b1,relu + @W2  -> h2pre
    k_fg1<<<NN / 16, 512, 0, stream>>>(x, deg, csr2, dinvt, w1h, w1l, b1, w2h, w2l, h2pre);
    // fused: conv2-agg(+b2,relu) + @Wo1+bo1,relu + @Wo2+bo2,relu -> a2
    k_fg2<<<NH / 16, 512, 0, stream>>>(h2pre, deg, csr2, dinvt, b2, o1h, o1l, bo1, o2h, o2l, bo2, a2);
    // fused final GEMM + per-graph softmax
    k_head<<<NG, 256, 0, stream>>>(a2, Wo3, bo3, out);
}

// Round 15
// 124.539 us; speedup vs baseline: 1.1961x; 1.1961x over previous
//
#include <hip/hip_runtime.h>
#include <math.h>

#define NN 32768      // nodes
#define NE 524288     // edges
#define NH 16384      // hosts
#define NG 64         // graphs
#define OUTC 2050     // 2 + 256*8
#define CAP 64        // padded-CSR slots per node (max degree ~40 for Binomial(E,1/N))

typedef _Float16 f16x8 __attribute__((ext_vector_type(8)));
typedef float f32x4 __attribute__((ext_vector_type(4)));

__device__ inline unsigned short f16bits(_Float16 h) { return __builtin_bit_cast(unsigned short, h); }

// async global->LDS, 16B per lane; LDS dest = wave-uniform base + lane*16 (linear)
__device__ inline void gll16(const ushort* g, ushort* l) {
    __builtin_amdgcn_global_load_lds(
        (const __attribute__((address_space(1))) unsigned int*)g,
        (__attribute__((address_space(3))) unsigned int*)l, 16, 0, 0);
}

// int64 edges stored little-endian have zero odd words (values < 2^31).
__device__ inline int detect64(const int* __restrict__ ei) {
    int o = 0;
#pragma unroll
    for (int i = 1; i < 32; i += 2) o |= ei[i];
    return o == 0;
}

// ---------------- weight prep (+ deg zeroing); runs FIRST ----------------
__global__ __launch_bounds__(256) void k_wprep(const float* __restrict__ W1, const float* __restrict__ W2,
                                               const float* __restrict__ Wo1, const float* __restrict__ Wo2,
                                               ushort* __restrict__ w1h, ushort* __restrict__ w1l,
                                               ushort* __restrict__ w2h, ushort* __restrict__ w2l,
                                               ushort* __restrict__ o1h, ushort* __restrict__ o1l,
                                               ushort* __restrict__ o2h, ushort* __restrict__ o2l,
                                               int* __restrict__ deg) {
    int b = blockIdx.x, t = threadIdx.x;
    int gid = b * 256 + t;
    if (gid < NN) deg[gid] = 0;
    const float* src; ushort *dh, *dl; int K, N, base;
    if (b < 128)      { src = W1;  dh = w1h; dl = w1l; K = 128; N = 256; base = b * 256; }
    else if (b < 192) { src = W2;  dh = w2h; dl = w2l; K = 256; N = 64;  base = (b - 128) * 256; }
    else if (b < 256) { src = Wo1; dh = o1h; dl = o1l; K = 64;  N = 256; base = (b - 192) * 256; }
    else              { src = Wo2; dh = o2h; dl = o2l; K = 256; N = 256; base = (b - 256) * 256; }
    int idx = base + t;          // index over [N][K], coalesced writes
    int n = idx / K, k = idx % K;
    float v = src[(size_t)k * N + n];
    _Float16 h = (_Float16)v;
    _Float16 l = (_Float16)(v - (float)h);
    dh[idx] = f16bits(h);
    dl[idx] = f16bits(l);
}

// ---------------- one-pass padded-CSR build: deg count + neighbor fill ----------------
__global__ __launch_bounds__(256) void k_build(const int* __restrict__ ei,
                                               int* __restrict__ deg, int* __restrict__ csr2) {
    int e = blockIdx.x * 256 + threadIdx.x;   // grid exact: NE/256 blocks
    int is64 = detect64(ei);
    int s = is64 ? ei[2 * e] : ei[e];
    int d = is64 ? ei[2 * NE + 2 * e] : ei[NE + e];
    int p = atomicAdd(&deg[d], 1);
    if (p < CAP) csr2[(d << 6) + p] = s;
}

// ================= fused GCN stage A: gather-agg(x) -> @W1+b1,relu -> @W2 =================
// Per block: 32 nodes. Phase0: conv1 aggregation (16 thr/node x 8 dims, 8-wide unroll),
// split pairs -> LDS AF. Stage1: T1[32,256]=relu(AF@W1T+b1); Stage2: h2pre[32,64]=T1@W2T.
__global__ __launch_bounds__(512, 4) void k_fg1(const float* __restrict__ x, const int* __restrict__ deg,
                                                const int* __restrict__ csr2,
                                                const ushort* __restrict__ B1h, const ushort* __restrict__ B1l,
                                                const float* __restrict__ b1v,
                                                const ushort* __restrict__ B2h, const ushort* __restrict__ B2l,
                                                float* __restrict__ C) {
    __shared__ ushort T1[2][32][256];    // 32.8 KB; stage1 uses cols [0,128) as AF
    __shared__ ushort Bs[2][256][32];    // 32 KB, linear (stage 1 & 2)

    int t = threadIdx.x;
    int bm = blockIdx.x * 32;
    int wave = t >> 6, lane = t & 63;
    int l15 = lane & 15, lk = lane >> 4;
    int lr = lane >> 2, lp = lane & 3;

    // ---------- phase 0: conv1 gather-aggregate (8-wide, inline rsqrt) ----------
    {
        int nl = t >> 4;                 // node-local 0..31
        int dgb = (t & 15) * 8;          // dim-group base
        int node = bm + nl;
        int dgv = deg[node];
        int n = min(dgv, CAP);
        float dd = rsqrtf((float)(dgv + 1));
        const float* xr = x + (size_t)node * 128 + dgb;
        float4 s0 = *(const float4*)xr;
        float4 s1 = *(const float4*)(xr + 4);
        float ac[8] = {s0.x * dd, s0.y * dd, s0.z * dd, s0.w * dd,
                       s1.x * dd, s1.y * dd, s1.z * dd, s1.w * dd};
        const int* cl = csr2 + (node << 6);
        int i = 0;
        for (; i + 8 <= n; i += 8) {
            int4 c0 = *(const int4*)(cl + i);
            int4 c1 = *(const int4*)(cl + i + 4);
            int ss[8] = {c0.x, c0.y, c0.z, c0.w, c1.x, c1.y, c1.z, c1.w};
            float wv[8]; float4 v0[8], v1[8];
#pragma unroll
            for (int j = 0; j < 8; ++j) wv[j] = rsqrtf((float)(deg[ss[j]] + 1));
#pragma unroll
            for (int j = 0; j < 8; ++j) {
                const float* p = x + (size_t)ss[j] * 128 + dgb;
                v0[j] = *(const float4*)p;
                v1[j] = *(const float4*)(p + 4);
            }
#pragma unroll
            for (int j = 0; j < 8; ++j) {
                ac[0] += v0[j].x * wv[j]; ac[1] += v0[j].y * wv[j];
                ac[2] += v0[j].z * wv[j]; ac[3] += v0[j].w * wv[j];
                ac[4] += v1[j].x * wv[j]; ac[5] += v1[j].y * wv[j];
                ac[6] += v1[j].z * wv[j]; ac[7] += v1[j].w * wv[j];
            }
        }
        for (; i + 4 <= n; i += 4) {
            int4 c0 = *(const int4*)(cl + i);
            int ss[4] = {c0.x, c0.y, c0.z, c0.w};
            float wv[4]; float4 v0[4], v1[4];
#pragma unroll
            for (int j = 0; j < 4; ++j) wv[j] = rsqrtf((float)(deg[ss[j]] + 1));
#pragma unroll
            for (int j = 0; j < 4; ++j) {
                const float* p = x + (size_t)ss[j] * 128 + dgb;
                v0[j] = *(const float4*)p;
                v1[j] = *(const float4*)(p + 4);
            }
#pragma unroll
            for (int j = 0; j < 4; ++j) {
                ac[0] += v0[j].x * wv[j]; ac[1] += v0[j].y * wv[j];
                ac[2] += v0[j].z * wv[j]; ac[3] += v0[j].w * wv[j];
                ac[4] += v1[j].x * wv[j]; ac[5] += v1[j].y * wv[j];
                ac[6] += v1[j].z * wv[j]; ac[7] += v1[j].w * wv[j];
            }
        }
        for (; i < n; ++i) {
            int s = cl[i];
            float wv = rsqrtf((float)(deg[s] + 1));
            const float* p = x + (size_t)s * 128 + dgb;
            float4 v0 = *(const float4*)p;
            float4 v1 = *(const float4*)(p + 4);
            ac[0] += v0.x * wv; ac[1] += v0.y * wv; ac[2] += v0.z * wv; ac[3] += v0.w * wv;
            ac[4] += v1.x * wv; ac[5] += v1.y * wv; ac[6] += v1.z * wv; ac[7] += v1.w * wv;
        }
        ushort hv[8], lv[8];
#pragma unroll
        for (int j = 0; j < 8; ++j) {
            float v = ac[j] * dd;
            _Float16 h = (_Float16)v;
            _Float16 l = (_Float16)(v - (float)h);
            hv[j] = f16bits(h); lv[j] = f16bits(l);
        }
        int cs = (((dgb >> 3) ^ (nl & 7))) * 8;   // swizzled 16B chunk
        *(uint4*)&T1[0][nl][cs] = *(const uint4*)hv;
        *(uint4*)&T1[1][nl][cs] = *(const uint4*)lv;
    }
    __syncthreads();

    // ---------- stage 1: K1=128, A resident in LDS; Bs staged via gll ----------
    int wc = wave;
    f32x4 acc1[2][2];
#pragma unroll
    for (int mi = 0; mi < 2; ++mi)
#pragma unroll
        for (int ni = 0; ni < 2; ++ni) acc1[mi][ni] = (f32x4){0.f, 0.f, 0.f, 0.f};

    for (int k0 = 0; k0 < 128; k0 += 32) {
#pragma unroll
        for (int i = 0; i < 4; ++i) {   // B1: 32 x 1KB units
            int u = wave * 4 + i;
            int buf = u >> 4, rb = (u & 15) * 16;
            int r = rb + lr;
            int cq = lp ^ ((r >> 1) & 3);
            gll16((buf ? B1l : B1h) + (size_t)r * 128 + k0 + cq * 8, &Bs[buf][rb][0]);
        }
        __syncthreads();
        f16x8 ah[2], al[2], bh[2], bl[2];
#pragma unroll
        for (int mi = 0; mi < 2; ++mi) {
            int r = mi * 16 + l15;
            int pos = (((k0 >> 3) + lk) ^ (r & 7)) * 8;
            ah[mi] = *(const f16x8*)&T1[0][r][pos];
            al[mi] = *(const f16x8*)&T1[1][r][pos];
        }
#pragma unroll
        for (int ni = 0; ni < 2; ++ni) {
            int r = wc * 32 + ni * 16 + l15;
            int pos = (lk ^ ((r >> 1) & 3)) * 8;
            bh[ni] = *(const f16x8*)&Bs[0][r][pos];
            bl[ni] = *(const f16x8*)&Bs[1][r][pos];
        }
#pragma unroll
        for (int mi = 0; mi < 2; ++mi)
#pragma unroll
            for (int ni = 0; ni < 2; ++ni) {
                acc1[mi][ni] = __builtin_amdgcn_mfma_f32_16x16x32_f16(ah[mi], bh[ni], acc1[mi][ni], 0, 0, 0);
                acc1[mi][ni] = __builtin_amdgcn_mfma_f32_16x16x32_f16(ah[mi], bl[ni], acc1[mi][ni], 0, 0, 0);
                acc1[mi][ni] = __builtin_amdgcn_mfma_f32_16x16x32_f16(al[mi], bh[ni], acc1[mi][ni], 0, 0, 0);
            }
        __syncthreads();
    }

    // T1 epilogue: bias + relu + split, swizzled store (overwrites AF region; stage1 done)
    float bb0 = b1v[wc * 32 + l15];
    float bb1 = b1v[wc * 32 + 16 + l15];
#pragma unroll
    for (int mi = 0; mi < 2; ++mi)
#pragma unroll
        for (int ni = 0; ni < 2; ++ni)
#pragma unroll
            for (int r = 0; r < 4; ++r) {
                int row = mi * 16 + lk * 4 + r;
                int col = wc * 32 + ni * 16 + l15;
                float v = fmaxf(acc1[mi][ni][r] + (ni ? bb1 : bb0), 0.f);
                _Float16 h = (_Float16)v;
                _Float16 l = (_Float16)(v - (float)h);
                int off = (((col >> 3) ^ (row & 7)) << 3) | (col & 7);
                T1[0][row][off] = f16bits(h);
                T1[1][row][off] = f16bits(l);
            }
    __syncthreads();

    // ---------- stage 2: K2=256, N2=64 ----------
    int rbase2 = (wave >> 2) * 16;
    int cbase2 = (wave & 3) * 16;
    f32x4 acc2 = (f32x4){0.f, 0.f, 0.f, 0.f};
    for (int k0 = 0; k0 < 256; k0 += 32) {
        {   // 8 x 1KB units (rows 0..63)
            int buf = wave >> 2, rb = (wave & 3) * 16;
            int r = rb + lr;
            int cq = lp ^ ((r >> 1) & 3);
            gll16((buf ? B2l : B2h) + (size_t)r * 256 + k0 + cq * 8, &Bs[buf][rb][0]);
        }
        __syncthreads();
        int row = rbase2 + l15;
        int off = (((k0 >> 3) + lk) ^ (row & 7)) << 3;
        f16x8 ah = *(const f16x8*)&T1[0][row][off];
        f16x8 al = *(const f16x8*)&T1[1][row][off];
        int r = cbase2 + l15;
        int pos = (lk ^ ((r >> 1) & 3)) * 8;
        f16x8 bh = *(const f16x8*)&Bs[0][r][pos];
        f16x8 bl = *(const f16x8*)&Bs[1][r][pos];
        acc2 = __builtin_amdgcn_mfma_f32_16x16x32_f16(ah, bh, acc2, 0, 0, 0);
        acc2 = __builtin_amdgcn_mfma_f32_16x16x32_f16(ah, bl, acc2, 0, 0, 0);
        acc2 = __builtin_amdgcn_mfma_f32_16x16x32_f16(al, bh, acc2, 0, 0, 0);
        __syncthreads();
    }
#pragma unroll
    for (int r = 0; r < 4; ++r) {
        int row = bm + rbase2 + lk * 4 + r;
        int col = cbase2 + l15;
        C[(size_t)row * 64 + col] = acc2[r];
    }
}

// ================= fused MLP stage B: conv2-agg(h2pre) -> @Wo1+bo1,relu -> @Wo2+bo2,relu =================
__global__ __launch_bounds__(512, 4) void k_fg2(const float* __restrict__ h2, const int* __restrict__ deg,
                                                const int* __restrict__ csr2, const float* __restrict__ b2v,
                                                const ushort* __restrict__ B1h, const ushort* __restrict__ B1l,
                                                const float* __restrict__ b1v,
                                                const ushort* __restrict__ B2h, const ushort* __restrict__ B2l,
                                                const float* __restrict__ bo2v,
                                                float* __restrict__ C) {
    __shared__ ushort T1[2][32][256];    // stage1 uses cols [0,64) as AF
    __shared__ ushort Bs[2][256][32];

    int t = threadIdx.x;
    int bm = blockIdx.x * 32;
    int wave = t >> 6, lane = t & 63;
    int l15 = lane & 15, lk = lane >> 4;
    int lr = lane >> 2, lp = lane & 3;

    // ---------- phase 0: conv2 gather-aggregate (host rows, 8-wide, inline rsqrt) ----------
    {
        int nl = t >> 4;
        int hr = bm + nl;                        // host row
        int node = ((hr >> 8) << 9) | (hr & 255);
        int dgb = (t & 15) * 4;
        int dgv = deg[node];
        int n = min(dgv, CAP);
        float dd = rsqrtf((float)(dgv + 1));
        float4 s = *(const float4*)(h2 + (size_t)node * 64 + dgb);
        float ac[4] = {s.x * dd, s.y * dd, s.z * dd, s.w * dd};
        const int* cl = csr2 + (node << 6);
        int i = 0;
        for (; i + 8 <= n; i += 8) {
            int4 c0 = *(const int4*)(cl + i);
            int4 c1 = *(const int4*)(cl + i + 4);
            int ss[8] = {c0.x, c0.y, c0.z, c0.w, c1.x, c1.y, c1.z, c1.w};
            float wv[8]; float4 vv[8];
#pragma unroll
            for (int j = 0; j < 8; ++j) wv[j] = rsqrtf((float)(deg[ss[j]] + 1));
#pragma unroll
            for (int j = 0; j < 8; ++j) vv[j] = *(const float4*)(h2 + (size_t)ss[j] * 64 + dgb);
#pragma unroll
            for (int j = 0; j < 8; ++j) {
                ac[0] += vv[j].x * wv[j]; ac[1] += vv[j].y * wv[j];
                ac[2] += vv[j].z * wv[j]; ac[3] += vv[j].w * wv[j];
            }
        }
        for (; i + 4 <= n; i += 4) {
            int4 c0 = *(const int4*)(cl + i);
            int ss[4] = {c0.x, c0.y, c0.z, c0.w};
            float wv[4]; float4 vv[4];
#pragma unroll
            for (int j = 0; j < 4; ++j) wv[j] = rsqrtf((float)(deg[ss[j]] + 1));
#pragma unroll
            for (int j = 0; j < 4; ++j) vv[j] = *(const float4*)(h2 + (size_t)ss[j] * 64 + dgb);
#pragma unroll
            for (int j = 0; j < 4; ++j) {
                ac[0] += vv[j].x * wv[j]; ac[1] += vv[j].y * wv[j];
                ac[2] += vv[j].z * wv[j]; ac[3] += vv[j].w * wv[j];
            }
        }
        for (; i < n; ++i) {
            int sI = cl[i];
            float wv = rsqrtf((float)(deg[sI] + 1));
            float4 vv = *(const float4*)(h2 + (size_t)sI * 64 + dgb);
            ac[0] += vv.x * wv; ac[1] += vv.y * wv; ac[2] += vv.z * wv; ac[3] += vv.w * wv;
        }
        ushort hv[4], lv[4];
#pragma unroll
        for (int j = 0; j < 4; ++j) {
            float v = fmaxf(ac[j] * dd + b2v[dgb + j], 0.f);
            _Float16 h = (_Float16)v;
            _Float16 l = (_Float16)(v - (float)h);
            hv[j] = f16bits(h); lv[j] = f16bits(l);
        }
        int c = dgb >> 3, half = (dgb >> 2) & 1;
        int pos = ((c ^ (nl & 7)) << 3) + half * 4;
        *(uint2*)&T1[0][nl][pos] = *(const uint2*)hv;
        *(uint2*)&T1[1][nl][pos] = *(const uint2*)lv;
    }
    __syncthreads();

    // ---------- stage 1: K1=64 ----------
    int wc = wave;
    f32x4 acc1[2][2];
#pragma unroll
    for (int mi = 0; mi < 2; ++mi)
#pragma unroll
        for (int ni = 0; ni < 2; ++ni) acc1[mi][ni] = (f32x4){0.f, 0.f, 0.f, 0.f};

    for (int k0 = 0; k0 < 64; k0 += 32) {
#pragma unroll
        for (int i = 0; i < 4; ++i) {   // B1: 32 x 1KB units
            int u = wave * 4 + i;
            int buf = u >> 4, rb = (u & 15) * 16;
            int r = rb + lr;
            int cq = lp ^ ((r >> 1) & 3);
            gll16((buf ? B1l : B1h) + (size_t)r * 64 + k0 + cq * 8, &Bs[buf][rb][0]);
        }
        __syncthreads();
        f16x8 ah[2], al[2], bh[2], bl[2];
#pragma unroll
        for (int mi = 0; mi < 2; ++mi) {
            int r = mi * 16 + l15;
            int pos = (((k0 >> 3) + lk) ^ (r & 7)) * 8;
            ah[mi] = *(const f16x8*)&T1[0][r][pos];
            al[mi] = *(const f16x8*)&T1[1][r][pos];
        }
#pragma unroll
        for (int ni = 0; ni < 2; ++ni) {
            int r = wc * 32 + ni * 16 + l15;
            int pos = (lk ^ ((r >> 1) & 3)) * 8;
            bh[ni] = *(const f16x8*)&Bs[0][r][pos];
            bl[ni] = *(const f16x8*)&Bs[1][r][pos];
        }
#pragma unroll
        for (int mi = 0; mi < 2; ++mi)
#pragma unroll
            for (int ni = 0; ni < 2; ++ni) {
                acc1[mi][ni] = __builtin_amdgcn_mfma_f32_16x16x32_f16(ah[mi], bh[ni], acc1[mi][ni], 0, 0, 0);
                acc1[mi][ni] = __builtin_amdgcn_mfma_f32_16x16x32_f16(ah[mi], bl[ni], acc1[mi][ni], 0, 0, 0);
                acc1[mi][ni] = __builtin_amdgcn_mfma_f32_16x16x32_f16(al[mi], bh[ni], acc1[mi][ni], 0, 0, 0);
            }
        __syncthreads();
    }

    // T1 epilogue
    float bb0 = b1v[wc * 32 + l15];
    float bb1 = b1v[wc * 32 + 16 + l15];
#pragma unroll
    for (int mi = 0; mi < 2; ++mi)
#pragma unroll
        for (int ni = 0; ni < 2; ++ni)
#pragma unroll
            for (int r = 0; r < 4; ++r) {
                int row = mi * 16 + lk * 4 + r;
                int col = wc * 32 + ni * 16 + l15;
                float v = fmaxf(acc1[mi][ni][r] + (ni ? bb1 : bb0), 0.f);
                _Float16 h = (_Float16)v;
                _Float16 l = (_Float16)(v - (float)h);
                int off = (((col >> 3) ^ (row & 7)) << 3) | (col & 7);
                T1[0][row][off] = f16bits(h);
                T1[1][row][off] = f16bits(l);
            }
    __syncthreads();

    // ---------- stage 2: K2=256, N2=256 ----------
    f32x4 acc2[2][2];
#pragma unroll
    for (int mi = 0; mi < 2; ++mi)
#pragma unroll
        for (int ni = 0; ni < 2; ++ni) acc2[mi][ni] = (f32x4){0.f, 0.f, 0.f, 0.f};

    for (int k0 = 0; k0 < 256; k0 += 32) {
#pragma unroll
        for (int i = 0; i < 4; ++i) {   // 32 x 1KB units
            int u = wave * 4 + i;
            int buf = u >> 4, rb = (u & 15) * 16;
            int r = rb + lr;
            int cq = lp ^ ((r >> 1) & 3);
            gll16((buf ? B2l : B2h) + (size_t)r * 256 + k0 + cq * 8, &Bs[buf][rb][0]);
        }
        __syncthreads();
        f16x8 ah[2], al[2], bh[2], bl[2];
#pragma unroll
        for (int mi = 0; mi < 2; ++mi) {
            int row = mi * 16 + l15;
            int off = (((k0 >> 3) + lk) ^ (row & 7)) << 3;
            ah[mi] = *(const f16x8*)&T1[0][row][off];
            al[mi] = *(const f16x8*)&T1[1][row][off];
        }
#pragma unroll
        for (int ni = 0; ni < 2; ++ni) {
            int r = wave * 32 + ni * 16 + l15;
            int pos = (lk ^ ((r >> 1) & 3)) * 8;
            bh[ni] = *(const f16x8*)&Bs[0][r][pos];
            bl[ni] = *(const f16x8*)&Bs[1][r][pos];
        }
#pragma unroll
        for (int mi = 0; mi < 2; ++mi)
#pragma unroll
            for (int ni = 0; ni < 2; ++ni) {
                acc2[mi][ni] = __builtin_amdgcn_mfma_f32_16x16x32_f16(ah[mi], bh[ni], acc2[mi][ni], 0, 0, 0);
                acc2[mi][ni] = __builtin_amdgcn_mfma_f32_16x16x32_f16(ah[mi], bl[ni], acc2[mi][ni], 0, 0, 0);
                acc2[mi][ni] = __builtin_amdgcn_mfma_f32_16x16x32_f16(al[mi], bh[ni], acc2[mi][ni], 0, 0, 0);
            }
        __syncthreads();
    }
    // epilogue: fp32 global write
    float cb0 = bo2v[wave * 32 + l15];
    float cb1 = bo2v[wave * 32 + 16 + l15];
#pragma unroll
    for (int mi = 0; mi < 2; ++mi)
#pragma unroll
        for (int ni = 0; ni < 2; ++ni)
#pragma unroll
            for (int r = 0; r < 4; ++r) {
                int row = bm + mi * 16 + lk * 4 + r;
                int col = wave * 32 + ni * 16 + l15;
                float v = fmaxf(acc2[mi][ni][r] + (ni ? cb1 : cb0), 0.f);
                C[(size_t)row * 256 + col] = v;
            }
}

// ---------------- fused head: logits = a2 @ Wo3 + bo3, then per-graph softmax ----------------
__global__ __launch_bounds__(256) void k_head(const float* __restrict__ A, const float* __restrict__ W,
                                              const float* __restrict__ bias, float* __restrict__ out) {
    __shared__ float Ws[2048];
    __shared__ float rm[4], rs[4];
    int g = blockIdx.x, t = threadIdx.x;
#pragma unroll
    for (int i = 0; i < 8; ++i) Ws[t + 256 * i] = W[t + 256 * i];   // [k][a] row-major
    __syncthreads();
    const float* arow = A + ((size_t)g * 256 + t) * 256;
    float acc[8];
#pragma unroll
    for (int a = 0; a < 8; ++a) acc[a] = bias[a];
    for (int k = 0; k < 256; k += 8) {
        float4 v0 = *(const float4*)(arow + k);
        float4 v1 = *(const float4*)(arow + k + 4);
#pragma unroll
        for (int a = 0; a < 8; ++a) {
            acc[a] += v0.x * Ws[(k + 0) * 8 + a] + v0.y * Ws[(k + 1) * 8 + a]
                    + v0.z * Ws[(k + 2) * 8 + a] + v0.w * Ws[(k + 3) * 8 + a]
                    + v1.x * Ws[(k + 4) * 8 + a] + v1.y * Ws[(k + 5) * 8 + a]
                    + v1.z * Ws[(k + 6) * 8 + a] + v1.w * Ws[(k + 7) * 8 + a];
        }
    }
    float m = acc[0];
#pragma unroll
    for (int i = 1; i < 8; ++i) m = fmaxf(m, acc[i]);
    for (int off = 32; off; off >>= 1) m = fmaxf(m, __shfl_xor(m, off));
    if ((t & 63) == 0) rm[t >> 6] = m;
    __syncthreads();
    m = fmaxf(fmaxf(rm[0], rm[1]), fmaxf(rm[2], rm[3]));
    float e[8];
    float s = 0.f;
#pragma unroll
    for (int i = 0; i < 8; ++i) { e[i] = expf(acc[i] - m); s += e[i]; }
    for (int off = 32; off; off >>= 1) s += __shfl_xor(s, off);
    if ((t & 63) == 0) rs[t >> 6] = s;
    __syncthreads();
    s = rs[0] + rs[1] + rs[2] + rs[3];
    float inv = 1.f / s;
    float* ob = out + (size_t)g * OUTC;
    if (t < 2) ob[t] = 0.f;
#pragma unroll
    for (int a = 0; a < 8; ++a) ob[2 + a * 256 + t] = e[a] * inv;
}

extern "C" void kernel_launch(void* const* d_in, const int* in_sizes, int n_in,
                              void* d_out, int out_size, void* d_ws, size_t ws_size,
                              hipStream_t stream) {
    const float* x   = (const float*)d_in[0];
    const int*   ei  = (const int*)d_in[1];
    const float* W1  = (const float*)d_in[3];
    const float* b1  = (const float*)d_in[4];
    const float* W2  = (const float*)d_in[5];
    const float* b2  = (const float*)d_in[6];
    const float* Wo1 = (const float*)d_in[7];
    const float* bo1 = (const float*)d_in[8];
    const float* Wo2 = (const float*)d_in[9];
    const float* bo2 = (const float*)d_in[10];
    const float* Wo3 = (const float*)d_in[11];
    const float* bo3 = (const float*)d_in[12];
    float* out = (float*)d_out;

    char* w = (char*)d_ws;
    float*  h2pre  = (float*) (w + (0ull  << 20));   // 8MB  [32768][64]
    float*  a2     = (float*) (w + (8ull  << 20));   // 16MB [16384][256]
    char* p = w + (24ull << 20);                     // transposed split weights
    ushort* w1h = (ushort*)p; p += 65536;
    ushort* w1l = (ushort*)p; p += 65536;
    ushort* w2h = (ushort*)p; p += 32768;
    ushort* w2l = (ushort*)p; p += 32768;
    ushort* o1h = (ushort*)p; p += 32768;
    ushort* o1l = (ushort*)p; p += 32768;
    ushort* o2h = (ushort*)p; p += 131072;
    ushort* o2l = (ushort*)p; p += 131072;
    char* misc = w + (25ull << 20);
    int* deg  = (int*)misc;            // 128KB
    int* csr2 = deg + NN;              // 8MB padded CSR [NN][CAP]

    // wprep: transposes weights AND zeroes deg
    k_wprep<<<512, 256, 0, stream>>>(W1, W2, Wo1, Wo2, w1h, w1l, w2h, w2l, o1h, o1l, o2h, o2l, deg);
    // one-pass padded-CSR build
    k_build<<<NE / 256, 256, 0, stream>>>(ei, deg, csr2);

    // fused: conv1-agg + @W1+b1,relu + @W2  -> h2pre
    k_fg1<<<NN / 32, 512, 0, stream>>>(x, deg, csr2, w1h, w1l, b1, w2h, w2l, h2pre);
    // fused: conv2-agg(+b2,relu) + @Wo1+bo1,relu + @Wo2+bo2,relu -> a2
    k_fg2<<<NH / 32, 512, 0, stream>>>(h2pre, deg, csr2, b2, o1h, o1l, bo1, o2h, o2l, bo2, a2);
    // fused final GEMM + per-graph softmax
    k_head<<<NG, 256, 0, stream>>>(a2, Wo3, bo3, out);
}